// Round 5
// baseline (130.644 us; speedup 1.0000x reference)
//
#include <hip/hip_runtime.h>
#include <hip/hip_fp16.h>
#include <math.h>

#define B_SZ 16
#define N_SZ 16384
#define T_FR 128      // frames per block
#define BLK  256      // threads per block: 2 lanes per frame
#define NBIN 65
#define NMEL 80
#define MST  66       // mags row stride (halves): 33 words -> 2-way alias = free
#define SST  82       // stage row stride (halves): 41 words, odd -> conflict-free
#define KN2  5        // taps per filter (true max support = 4; 5 for safety)

// ---------------- compile-time math ----------------

// cos(k*pi/64) for k = 0..32
constexpr float QC[33] = {
  1.0f,            0.99879545620f, 0.99518472667f, 0.98917650996f,
  0.98078528040f,  0.97003125319f, 0.95694033573f, 0.94154406518f,
  0.92387953251f,  0.90398929312f, 0.88192126435f, 0.85772861000f,
  0.83146961230f,  0.80320753148f, 0.77301045336f, 0.74095112535f,
  0.70710678119f,  0.67155895485f, 0.63439328416f, 0.59569930449f,
  0.55557023302f,  0.51410274419f, 0.47139673683f, 0.42755509343f,
  0.38268343236f,  0.33688985339f, 0.29028467725f, 0.24298017990f,
  0.19509032202f,  0.14673047446f, 0.09801714033f, 0.04906767433f,
  0.0f
};
__host__ __device__ constexpr float cosi(int k) {   // cos(pi*k/64)
  k = ((k % 128) + 128) % 128;
  return (k <= 32) ? QC[k]
       : (k <= 64) ? -QC[64 - k]
       : (k <= 96) ? -QC[k - 64]
       : QC[128 - k];
}
__host__ __device__ constexpr float sini(int k) { return cosi(k - 32); }
__host__ __device__ constexpr float hannw(int n) { return 0.5f - 0.5f * cosi(n); }
__host__ __device__ constexpr int rev6(int m) {
  return ((m & 1) << 5) | ((m & 2) << 3) | ((m & 4) << 1) |
         ((m & 8) >> 1) | ((m & 16) >> 3) | ((m & 32) >> 5);
}

constexpr double cln(double x) {          // constexpr natural log, ~1e-16
  int k = 0;
  while (x > 1.5)  { x *= 0.5; ++k; }
  while (x < 0.75) { x *= 2.0; --k; }
  const double y = (x - 1.0) / (x + 1.0);
  const double y2 = y * y;
  double t = y, s = 0.0;
  for (int i = 0; i < 40; ++i) { s += t / (double)(2 * i + 1); t *= y2; }
  return 2.0 * s + (double)k * 0.69314718055994530942;
}
constexpr double melf(double f) { return 1127.0 * cln(1.0 + f / 700.0); }

// sparse mel filterbank; filters 0..39 live in bins <=15, 40..79 in bins 12..64
struct MelTab2 {
  int   kb[NMEL];
  float w[NMEL][KN2];
  bool  ok0, ok1, okw;
  constexpr MelTab2() : kb{}, w{}, ok0(true), ok1(true), okw(true) {
    const double mlo = melf(80.0), mhi = melf(7600.0);
    const double dm  = (mhi - mlo) / 81.0;
    for (int j = 0; j < NMEL; ++j) {
      const double lower = mlo + dm * (double)j;
      const double upper = lower + 2.0 * dm;
      int b0 = -1, b1 = -1;
      for (int k = 1; k < NBIN; ++k) {
        const double m = melf(125.0 * (double)k);
        if (m - lower > 0.0 && upper - m > 0.0) { if (b0 < 0) b0 = k; b1 = k; }
      }
      if (b0 < 0) { b0 = 1; b1 = 0; }          // empty filter -> all-zero weights
      kb[j] = b0;
      for (int r = 0; r < KN2; ++r) {
        const int k = b0 + r;
        double ww = 0.0;
        if (k <= b1) {
          const double m = melf(125.0 * (double)k);
          const double a = (m - lower) / dm, c = (upper - m) / dm;
          ww = a < c ? a : c; if (ww < 0.0) ww = 0.0;
        }
        w[j][r] = (float)ww;
      }
      if (b1 - b0 + 1 > KN2) okw = false;
      if (j < 40) { if (b1 > 15) ok0 = false; }
      else        { if (b0 < 12 || b1 > 64) ok1 = false; }
    }
  }
};
constexpr MelTab2 MT{};
static_assert(MT.okw, "mel filter support wider than KN2");
static_assert(MT.ok0, "low-half filters exceed bin 15");
static_assert(MT.ok1, "high-half filters outside bins 12..64");

// ---------------- FFT (32 complex per lane) ----------------

template <int LEN>
__device__ __forceinline__ void fft_stage32(float (&zr)[32], float (&zi)[32]) {
#pragma unroll
  for (int i = 0; i < 32; i += LEN) {
#pragma unroll
    for (int j = 0; j < LEN / 2; ++j) {
      const int   q  = 128 * j / LEN;
      const float wr = cosi(q);
      const float wi = -sini(q);
      const int   a = i + j, bb = i + j + LEN / 2;
      const float br = zr[bb], bi = zi[bb];
      const float tr = wr * br - wi * bi;
      const float ti = wr * bi + wi * br;
      zr[bb] = zr[a] - tr;
      zi[bb] = zi[a] - ti;
      zr[a] += tr;
      zi[a] += ti;
    }
  }
}

// NOTE: no min-waves launch bound (R2: VGPR cap 84 -> scratch spill, +375 MB HBM).
__global__ __launch_bounds__(BLK) void melspec_kernel(const float* __restrict__ x,
                                                      float* __restrict__ out) {
  __shared__ float  xs[BLK];                 // input chunk (128 frames + 127 pad + 1)
  __shared__ __half mags[T_FR * MST];        // [t][k] fp16 magnitudes
  __shared__ __half stage[T_FR * SST];       // [t][c] mel 0..79 at 0..79, x at 80

  const int i  = threadIdx.x;
  const int t0 = blockIdx.x * T_FR;
  const int b  = blockIdx.y;
  const float* xrow = x + (size_t)b * N_SZ;

  // ---- phase 0: input chunk (zero-pad past row end; no wrap across rows) ----
  {
    const int g = t0 + i;
    xs[i] = (g < N_SZ) ? xrow[g] : 0.0f;
  }
  __syncthreads();

  // ---- phase 1: pair-split 128-pt real FFT. lane h holds Z[32h..32h+31] ----
  const int t = i >> 1, h = i & 1;
  float zr[32], zi[32];
  {
    const float* xf = xs + t;
#pragma unroll
    for (int m = 0; m < 32; ++m) {
      const int rm = rev6(m);                // even (bit5 of input index = h)
      const int n0 = 2 * rm + 2 * h;         // sample index (runtime, h-dep)
      const float w0 = h ? hannw(2 * rm + 2) : hannw(2 * rm);
      const float w1 = h ? hannw(2 * rm + 3) : hannw(2 * rm + 1);
      zr[m] = xf[n0]     * w0;
      zi[m] = xf[n0 + 1] * w1;
    }
  }
  fft_stage32<2>(zr, zi);
  fft_stage32<4>(zr, zi);
  fft_stage32<8>(zr, zi);
  fft_stage32<16>(zr, zi);
  fft_stage32<32>(zr, zi);

  // stage LEN=64 cross-lane: butterfly j pairs Z[j] (lane0) with Z[j+32] (lane1)
  {
    const float sgn = h ? -1.0f : 1.0f;
#pragma unroll
    for (int j = 0; j < 32; ++j) {
      const float or_ = __shfl_xor(zr[j], 1, 64);
      const float oi_ = __shfl_xor(zi[j], 1, 64);
      const float zbr = h ? zr[j] : or_;     // zb = lane1's value
      const float zbi = h ? zi[j] : oi_;
      const float zar = h ? or_ : zr[j];     // za = lane0's value
      const float zai = h ? oi_ : zi[j];
      const float wr = cosi(2 * j), wi = -sini(2 * j);
      const float tr = wr * zbr - wi * zbi;
      const float ti = wr * zbi + wi * zbr;
      zr[j] = fmaf(sgn, tr, zar);
      zi[j] = fmaf(sgn, ti, zai);
    }
  }

  // ---- real split + magnitude: lane0 -> k=0..31, lane1 -> k=32..64 ----
  float mg[32];
  float m64 = 0.0f;
  {
    // j=0: exchange Z[0]<->Z[32]; lane0: k=0, lane1: k=32 and k=64
    const float er0 = __shfl_xor(zr[0], 1, 64);
    const float ei0 = __shfl_xor(zi[0], 1, 64);
    const float mag0  = fabsf(zr[0] + zi[0]);                 // k=0   (lane0)
    const float mag32 = sqrtf(zr[0] * zr[0] + zi[0] * zi[0]); // k=32  (lane1)
    mg[0] = h ? mag32 : mag0;
    m64   = fabsf(er0 - ei0);                                 // k=64  (lane1; from Z[0])
#pragma unroll
    for (int j = 1; j < 32; ++j) {
      // both lanes exchange local (32-j): lane0 gets Z[64-j], lane1 gets Z[32-j]
      const float er = __shfl_xor(zr[32 - j], 1, 64);
      const float ei = __shfl_xor(zi[32 - j], 1, 64);
      const float Ar = zr[j], Ai = zi[j];    // A = Z[k&63] (own local j)
      const float Br = er,    Bi = ei;       // B = Z[(64-k)&63] (received)
      const float c = h ? -sini(j) : cosi(j);  // cosi(32+j) = -sini(j)
      const float s = h ?  cosi(j) : sini(j);  // sini(32+j) =  cosi(j)
      const float t1 = Ar + Br, t2 = Ai + Bi, t3 = Ar - Br, t4 = Ai - Bi;
      float Xr = fmaf(c, t2, t1); Xr = fmaf(-s, t3, Xr);
      float Xi = fmaf(-c, t3, t4); Xi = fmaf(-s, t2, Xi);
      mg[j] = 0.5f * sqrtf(Xr * Xr + Xi * Xi);
    }
  }
  // write mags (bin k at half t*MST+k): 16 packed half2 + lane1's k=64
  {
    __half2* mrow = (__half2*)(mags + t * MST + 32 * h);
#pragma unroll
    for (int p = 0; p < 16; ++p)
      mrow[p] = __floats2half2_rn(mg[2 * p], mg[2 * p + 1]);
    if (h) mags[t * MST + 64] = __float2half(m64);
  }
  __syncthreads();

  // ---- phase 2: mel. H is WAVE-uniform (waves 0-1: filters 0..39, 2-3: 40..79)
  {
    const int t2 = i & 127;
    const int H  = i >> 7;
    __half* srow = stage + t2 * SST;
    if (H == 0) {
      float m0[16];
      const __half2* mp = (const __half2*)(mags + t2 * MST);
#pragma unroll
      for (int p = 0; p < 8; ++p) {
        const float2 f = __half22float2(mp[p]);
        m0[2 * p] = f.x; m0[2 * p + 1] = f.y;
      }
      __half2* sp = (__half2*)(srow);        // channels 0..39 (even half offsets)
#pragma unroll
      for (int q = 0; q < 20; ++q) {
        float acc[2];
#pragma unroll
        for (int e = 0; e < 2; ++e) {
          const int j = 2 * q + e;
          float a = 0.0f;
#pragma unroll
          for (int r = 0; r < KN2; ++r) {
            const float ww = MT.w[j][r];     // constexpr -> folds; w==0 taps vanish
            if (ww != 0.0f) {
              int idx = MT.kb[j] + r; if (idx > 15) idx = 15;
              a = fmaf(ww, m0[idx], a);
            }
          }
          acc[e] = a;
        }
        sp[q] = __floats2half2_rn(acc[0], acc[1]);
      }
      srow[80] = __float2half(xs[t2]);       // x channel
    } else {
      float m1[54];                          // bins 12..65 (65 = never-used pad)
      const __half2* mp = (const __half2*)(mags + t2 * MST + 12);
#pragma unroll
      for (int p = 0; p < 27; ++p) {
        const float2 f = __half22float2(mp[p]);
        m1[2 * p] = f.x; m1[2 * p + 1] = f.y;
      }
      __half2* sp = (__half2*)(srow + 40);   // channels 40..79
#pragma unroll
      for (int q = 0; q < 20; ++q) {
        float acc[2];
#pragma unroll
        for (int e = 0; e < 2; ++e) {
          const int j = 40 + 2 * q + e;
          float a = 0.0f;
#pragma unroll
          for (int r = 0; r < KN2; ++r) {
            const float ww = MT.w[j][r];
            if (ww != 0.0f) {
              int idx = MT.kb[j] + r - 12; if (idx > 52) idx = 52;
              a = fmaf(ww, m1[idx], a);
            }
          }
          acc[e] = a;
        }
        sp[q] = __floats2half2_rn(acc[0], acc[1]);
      }
    }
  }
  __syncthreads();

  // ---- phase 3: coalesced output. flat = it*256 + i = t*81 + c ----
  {
    float* orow = out + ((size_t)b * N_SZ + t0) * 81;
    int tt = (i >= 243) ? 3 : (i >= 162) ? 2 : (i >= 81) ? 1 : 0;
    int cc = i - 81 * tt;
    int flat = i;
#pragma unroll 1
    for (int it = 0; it < 41; ++it) {
      if (flat < T_FR * 81) {
        const int m = (cc == 0) ? 80 : cc - 1;   // channel 0 = x (stage half 80)
        orow[flat] = __half2float(stage[tt * SST + m]);
      }
      flat += BLK;
      cc += 13; tt += 3;                     // 256 = 3*81 + 13
      if (cc >= 81) { cc -= 81; ++tt; }
    }
  }
}

extern "C" void kernel_launch(void* const* d_in, const int* in_sizes, int n_in,
                              void* d_out, int out_size, void* d_ws, size_t ws_size,
                              hipStream_t stream) {
  const float* x = (const float*)d_in[0];
  float* out = (float*)d_out;
  dim3 grid(N_SZ / T_FR, B_SZ);
  dim3 block(BLK);
  hipLaunchKernelGGL(melspec_kernel, grid, block, 0, stream, x, out);
}

// Round 6
// 113.192 us; speedup vs baseline: 1.1542x; 1.1542x over previous
//
#include <hip/hip_runtime.h>
#include <hip/hip_fp16.h>
#include <math.h>

#define B_SZ 16
#define N_SZ 16384
#define T_FR 64       // frames per block (= block size = ONE wave)
#define NBIN 65       // spectral bins
#define NMEL 80
#define ST   83       // stage row stride in halves (odd -> conflict-free)
#define KN   6        // taps per mel filter (true max support = 5 bins)

// ---------------- compile-time math ----------------

// cos(k*pi/64) for k = 0..32 (quarter-wave table for 128-pt FFT)
constexpr float QC[33] = {
  1.0f,            0.99879545620f, 0.99518472667f, 0.98917650996f,
  0.98078528040f,  0.97003125319f, 0.95694033573f, 0.94154406518f,
  0.92387953251f,  0.90398929312f, 0.88192126435f, 0.85772861000f,
  0.83146961230f,  0.80320753148f, 0.77301045336f, 0.74095112535f,
  0.70710678119f,  0.67155895485f, 0.63439328416f, 0.59569930449f,
  0.55557023302f,  0.51410274419f, 0.47139673683f, 0.42755509343f,
  0.38268343236f,  0.33688985339f, 0.29028467725f, 0.24298017990f,
  0.19509032202f,  0.14673047446f, 0.09801714033f, 0.04906767433f,
  0.0f
};

__host__ __device__ constexpr float cosi(int k) {   // cos(pi*k/64)
  k = ((k % 128) + 128) % 128;
  return (k <= 32) ? QC[k]
       : (k <= 64) ? -QC[64 - k]
       : (k <= 96) ? -QC[k - 64]
       : QC[128 - k];
}
__host__ __device__ constexpr float sini(int k) { return cosi(k - 32); }  // sin(pi*k/64)
__host__ __device__ constexpr float hannw(int n) { return 0.5f - 0.5f * cosi(n); }
__host__ __device__ constexpr int rev6(int m) {
  return ((m & 1) << 5) | ((m & 2) << 3) | ((m & 4) << 1) |
         ((m & 8) >> 1) | ((m & 16) >> 3) | ((m & 32) >> 5);
}

// constexpr natural log (double), range-reduced atanh series; ~1e-16 accurate
constexpr double cln(double x) {
  int k = 0;
  while (x > 1.5)  { x *= 0.5; ++k; }
  while (x < 0.75) { x *= 2.0; --k; }
  const double y = (x - 1.0) / (x + 1.0);
  const double y2 = y * y;
  double t = y, s = 0.0;
  for (int i = 0; i < 40; ++i) { s += t / (double)(2 * i + 1); t *= y2; }
  return 2.0 * s + (double)k * 0.69314718055994530942;
}
constexpr double melf(double f) { return 1127.0 * cln(1.0 + f / 700.0); }

// compile-time sparse mel filterbank: per filter j, start bin kbe[j] + KN weights
struct MelTab {
  int   kbe[NMEL];
  float w[NMEL][KN];
  constexpr MelTab() : kbe{}, w{} {
    const double mlo = melf(80.0), mhi = melf(7600.0);
    const double dm  = (mhi - mlo) / 81.0;     // 82 edges -> 81 gaps
    for (int j = 0; j < NMEL; ++j) {
      const double lower = mlo + dm * (double)j;
      const double upper = lower + 2.0 * dm;
      int kb = 64;
      for (int k = 1; k < NBIN; ++k) {
        const double m = melf(125.0 * (double)k);
        const double a = m - lower, b2 = upper - m;
        if ((a < b2 ? a : b2) > 0.0) { kb = k; break; }
      }
      if (kb > NBIN - KN) kb = NBIN - KN;      // keep kb+KN-1 <= 64
      kbe[j] = kb;
      for (int r = 0; r < KN; ++r) {
        const int k = kb + r;
        double ww = 0.0;
        if (k >= 1 && k < NBIN) {
          const double m = melf(125.0 * (double)k);
          const double a = (m - lower) / dm, b2 = (upper - m) / dm;
          ww = a < b2 ? a : b2;
          if (ww < 0.0) ww = 0.0;
        }
        w[j][r] = (float)ww;
      }
    }
  }
};
constexpr MelTab MT{};

// ---------------- FFT ----------------

template <int LEN>
__device__ __forceinline__ void fft_stage(float (&zr)[64], float (&zi)[64]) {
#pragma unroll
  for (int i = 0; i < 64; i += LEN) {
#pragma unroll
    for (int j = 0; j < LEN / 2; ++j) {
      const int   q  = 128 * j / LEN;          // twiddle e^{-2*pi*i*j/LEN}
      const float wr = cosi(q);
      const float wi = -sini(q);
      const int   a = i + j, bb = i + j + LEN / 2;
      const float br = zr[bb], bi = zi[bb];
      const float tr = wr * br - wi * bi;
      const float ti = wr * bi + wi * br;
      zr[bb] = zr[a] - tr;
      zi[bb] = zi[a] - ti;
      zr[a] += tr;
      zi[a] += ti;
    }
  }
}

// Single-wave blocks: s_barrier degenerates to an in-wave waitcnt (no inter-wave
// drain), and ~12 independent waves/CU self-de-synchronize so VALU / LDS / store
// phases overlap across waves. No min-waves launch bound (R2: VGPR cap -> spill).
__global__ __launch_bounds__(T_FR) void melspec_kernel(const float* __restrict__ x,
                                                       float* __restrict__ out) {
  __shared__ float  xs[T_FR + 128];
  __shared__ __half stage[T_FR * ST];          // [t][c]: half 0 = x, 1+j = mel_j

  const int tid = threadIdx.x;
  const int t0  = blockIdx.x * T_FR;
  const int b   = blockIdx.y;
  const float* xrow = x + (size_t)b * N_SZ;

  // ---- load input chunk (zero-pad past row end; pad does NOT wrap rows) ----
  for (int i = tid; i < T_FR + 128; i += T_FR) {
    const int g = t0 + i;
    xs[i] = (g < N_SZ) ? xrow[g] : 0.0f;
  }
  __syncthreads();

  // ---- per-thread 128-pt real FFT (as 64-pt complex), window folded in ----
  float zr[64], zi[64];
  {
    const float* xf = xs + tid;
#pragma unroll
    for (int m = 0; m < 64; ++m) {
      const int rm = rev6(m);                  // compile-time bit-reversal
      zr[m] = xf[2 * rm]     * hannw(2 * rm);
      zi[m] = xf[2 * rm + 1] * hannw(2 * rm + 1);
    }
  }
  fft_stage<2>(zr, zi);
  fft_stage<4>(zr, zi);
  fft_stage<8>(zr, zi);
  fft_stage<16>(zr, zi);
  fft_stage<32>(zr, zi);
  fft_stage<64>(zr, zi);

  // ---- real split + magnitude, kept in registers ----
  float mag[NBIN];
#pragma unroll
  for (int k = 0; k < NBIN; ++k) {
    const int ka = k & 63, kc = (64 - k) & 63;
    const float Ar = zr[ka], Ai = zi[ka];
    const float Br = zr[kc], Bi = zi[kc];
    const float c = cosi(k), s = sini(k);
    const float Xr = (Ar + Br) + c * (Ai + Bi) - s * (Ar - Br);
    const float Xi = (Ai - Bi) - c * (Ar - Br) - s * (Ai + Bi);
    mag[k] = 0.5f * sqrtf(Xr * Xr + Xi * Xi);
  }

  // ---- mel matvec: compile-time sparse taps, register mags -> fp16 stage ----
  {
    __half* srow = stage + tid * ST;
    srow[0] = __float2half(xs[tid]);           // channel 0 = x
#pragma unroll
    for (int j = 0; j < NMEL; ++j) {
      const int kb = MT.kbe[j];                // compile-time after unroll
      float acc = MT.w[j][0] * mag[kb];
#pragma unroll
      for (int r = 1; r < KN; ++r)
        acc = fmaf(MT.w[j][r], mag[kb + r], acc);  // zero-weight taps fold away
      srow[1 + j] = __float2half(acc);
    }
  }

  __syncthreads();

  // ---- coalesced output: flat = i*64 + tid = t*81 + c, incremental (t,c) ----
  float* orow = out + ((size_t)b * N_SZ + t0) * 81;
  int t = 0;
  int c = tid;                                 // tid < 64 < 81 -> t starts at 0
  for (int i = 0; i < 81; ++i) {               // 64*81 elements, exactly 81 iters
    orow[i * T_FR + tid] = __half2float(stage[t * ST + c]);
    c += T_FR;                                 // step = block size (64)
    if (c >= 81) { c -= 81; ++t; }
  }
}

extern "C" void kernel_launch(void* const* d_in, const int* in_sizes, int n_in,
                              void* d_out, int out_size, void* d_ws, size_t ws_size,
                              hipStream_t stream) {
  const float* x = (const float*)d_in[0];
  float* out = (float*)d_out;
  dim3 grid(N_SZ / T_FR, B_SZ);
  dim3 block(T_FR);
  hipLaunchKernelGGL(melspec_kernel, grid, block, 0, stream, x, out);
}